// Round 7
// baseline (153.460 us; speedup 1.0000x reference)
//
#include <hip/hip_runtime.h>
#include <cstdint>

#define BATCH 64
#define NPIX 65536
#define TOPK 16384
#define NB 256        // value bins: key = floor(v*256), v in [0,1)
#define SEGS 32       // k1 blocks per batch
#define WLO 186       // candidate window low bin  (threshold bin = 192 +- ~1)
#define WHI 198       // candidate window high bin (13 bins, ~104 hits/block)
#define CAPB 192      // per-block candidate slots (expected 104, sigma ~10)
#define FCAP 1024     // k4 threshold-bin candidate capacity (expected ~256)

__device__ __forceinline__ float block_reduce(float acc) {
    __shared__ float w[4];
    #pragma unroll
    for (int off = 32; off > 0; off >>= 1) acc += __shfl_down(acc, off, 64);
    if ((threadIdx.x & 63) == 0) w[threadIdx.x >> 6] = acc;
    __syncthreads();
    return w[0] + w[1] + w[2] + w[3];
}

// p = softmax(a0,a1)[0] = sigmoid(d), d = a0-a1.
// lp = log p = min(d,0)-t ; llp = log(1-p) = -max(d,0)-t, t = log(1+exp(-|d|)).
__device__ __forceinline__ void bce_from_d(float d, float& lp, float& llp) {
    float t = __logf(1.f + __expf(-fabsf(d)));
    lp  = fmaxf(fminf(d, 0.f) - t, -100.f);
    llp = fmaxf(-fmaxf(d, 0.f) - t, -100.f);
}

__device__ __forceinline__ int vkey(float v) {
    return (int)fminf(v * 256.0f, 255.0f);   // monotone bucket map, v in [0,1)
}

// ---------------------------------------------------------------------------
// K1: one pass over all 80MB. SEGS blocks/batch, 2048 px each.
// Outputs (all plain stores, fully written -> no pre-zero):
//   gc/gs : per-block 256-bin {count, sum(diff)} sub-histogram
//   pk1   : per-block sum(llp)
//   candw : per-block fixed-slot list of window hits {vbits, px, diff}
//   gcc   : per-block raw hit count (k4 checks overflow)
// Block 0 zeroes out[0] (k4's atomicAdd target).
// ---------------------------------------------------------------------------
__global__ __launch_bounds__(256) void k1_hist_base(
    const float4* __restrict__ sc, const float4* __restrict__ gn,
    const float2* __restrict__ tokp,
    uint32_t* __restrict__ gc, float* __restrict__ gs,
    float* __restrict__ pk1,
    uint32_t* __restrict__ candw, uint32_t* __restrict__ gcc,
    float* __restrict__ out)
{
    __shared__ uint32_t hc[NB];
    __shared__ float hs[NB];
    __shared__ uint32_t cbuf[CAPB * 3];
    __shared__ uint32_t ccount;
    const int tid = threadIdx.x;
    hc[tid] = 0u; hs[tid] = 0.f;
    if (tid == 0) {
        ccount = 0u;
        if (blockIdx.x == 0) out[0] = 0.f;
    }
    __syncthreads();

    const int b   = blockIdx.x >> 5;
    const int seg = blockIdx.x & (SEGS - 1);
    const int pairbase = b * (NPIX / 2) + seg * 1024;   // 1024 pairs / block
    float acc = 0.f;

    #pragma unroll
    for (int it = 0; it < 4; ++it) {
        int j = pairbase + it * 256 + tid;
        float4 s = sc[j];
        float4 g = gn[j];
        float2 tk = tokp[j];
        int px0 = (j - b * (NPIX / 2)) * 2;             // batch-local pixel idx
        {
            float d = (s.x + g.x) - (s.y + g.y);
            float lp, llp; bce_from_d(d, lp, llp);
            acc += llp;
            float diff = lp - llp;
            int k = vkey(tk.x);
            atomicAdd(&hc[k], 1u);
            atomicAdd(&hs[k], diff);
            if (k >= WLO && k <= WHI) {
                uint32_t p = atomicAdd(&ccount, 1u);
                if (p < CAPB) {
                    cbuf[p * 3]     = __float_as_uint(tk.x);
                    cbuf[p * 3 + 1] = (uint32_t)px0;
                    cbuf[p * 3 + 2] = __float_as_uint(diff);
                }
            }
        }
        {
            float d = (s.z + g.z) - (s.w + g.w);
            float lp, llp; bce_from_d(d, lp, llp);
            acc += llp;
            float diff = lp - llp;
            int k = vkey(tk.y);
            atomicAdd(&hc[k], 1u);
            atomicAdd(&hs[k], diff);
            if (k >= WLO && k <= WHI) {
                uint32_t p = atomicAdd(&ccount, 1u);
                if (p < CAPB) {
                    cbuf[p * 3]     = __float_as_uint(tk.y);
                    cbuf[p * 3 + 1] = (uint32_t)(px0 + 1);
                    cbuf[p * 3 + 2] = __float_as_uint(diff);
                }
            }
        }
    }
    __syncthreads();
    const size_t o = (size_t)blockIdx.x * NB + tid;   // [b][seg][bin]
    gc[o] = hc[tid];
    gs[o] = hs[tid];
    const uint32_t n = ccount;
    if (tid == 0) gcc[blockIdx.x] = n;                // raw count (overflow check)
    const uint32_t m = min(n, (uint32_t)CAPB);
    const size_t cbase = (size_t)blockIdx.x * CAPB * 3;
    for (uint32_t i = tid; i < m * 3; i += 256) candw[cbase + i] = cbuf[i];
    float tot = block_reduce(acc);
    if (tid == 0) pk1[blockIdx.x] = tot;
}

// ---------------------------------------------------------------------------
// K4: one block per batch. Merge sub-hists -> suffix scan -> sb/rem/sa.
// Fast path (sb in window, no overflow): filter stored candidates to
// key==sb, exact rank under (value desc, index asc), add stored diffs.
// Fallback (never expected): direct exact rescan of this batch's s_map.
// Adds sa + sum(pk1 segment) and atomicAdds -total into pre-zeroed out.
// ---------------------------------------------------------------------------
__global__ __launch_bounds__(256) void k4_finalize(
    const uint32_t* __restrict__ gc, const float* __restrict__ gs,
    const uint32_t* __restrict__ candw, const uint32_t* __restrict__ gcc,
    const float* __restrict__ pk1,
    const float4* __restrict__ tok4,
    const float2* __restrict__ sc2, const float2* __restrict__ gn2,
    float* __restrict__ out)
{
    __shared__ uint32_t sufc[2][NB];
    __shared__ float    sufs[2][NB];
    __shared__ uint32_t fvb[FCAP];
    __shared__ uint32_t fvi[FCAP];
    __shared__ float    fdf[FCAP];
    __shared__ uint32_t fcnt;
    __shared__ int      sh_sb;
    __shared__ uint32_t sh_rem;
    __shared__ float    sh_sa;
    __shared__ int      sh_ovf;

    const int b = blockIdx.x, tid = threadIdx.x;
    if (tid == 0) { fcnt = 0u; sh_sb = 0; sh_rem = 0u; sh_sa = 0.f; sh_ovf = 0; }

    // merge sub-histograms (coalesced) + overflow detection
    uint32_t c = 0; float s = 0.f;
    for (int sg = 0; sg < SEGS; ++sg) {
        size_t o = (size_t)(b * SEGS + sg) * NB + tid;
        c += gc[o];
        s += gs[o];
    }
    sufc[0][tid] = c; sufs[0][tid] = s;
    __syncthreads();
    if (tid < SEGS && gcc[b * SEGS + tid] > CAPB) sh_ovf = 1;

    int cur = 0;
    #pragma unroll
    for (int off = 1; off < NB; off <<= 1) {
        uint32_t cc = sufc[cur][tid];
        float ss = sufs[cur][tid];
        if (tid + off < NB) { cc += sufc[cur][tid + off]; ss += sufs[cur][tid + off]; }
        sufc[cur ^ 1][tid] = cc; sufs[cur ^ 1][tid] = ss;
        cur ^= 1;
        __syncthreads();
    }
    // S[bin] = #elements with key >= bin; unique sb: S[sb] >= K > S[sb+1]
    uint32_t Sme = sufc[cur][tid];
    uint32_t Snx = (tid < NB - 1) ? sufc[cur][tid + 1] : 0u;
    if (Sme >= TOPK && Snx < TOPK) {
        sh_sb  = tid;
        sh_rem = TOPK - Snx;
        sh_sa  = (tid < NB - 1) ? sufs[cur][tid + 1] : 0.f;
    }
    __syncthreads();
    const int sb = sh_sb;
    const uint32_t rem = min(sh_rem, (uint32_t)NPIX);
    const bool fast = (sb >= WLO && sb <= WHI && sh_ovf == 0);

    if (fast) {
        // stream stored window candidates, keep key == sb
        for (int sg = 0; sg < SEGS; ++sg) {
            uint32_t cc2 = min(gcc[b * SEGS + sg], (uint32_t)CAPB);
            size_t base = (size_t)(b * SEGS + sg) * CAPB * 3;
            if ((uint32_t)tid < cc2) {
                uint32_t vb = candw[base + tid * 3];
                uint32_t vi = candw[base + tid * 3 + 1];
                uint32_t df = candw[base + tid * 3 + 2];
                if (vkey(__uint_as_float(vb)) == sb) {
                    uint32_t p = atomicAdd(&fcnt, 1u);
                    if (p < FCAP) {
                        fvb[p] = vb;
                        fvi[p] = vi & (NPIX - 1);
                        fdf[p] = __uint_as_float(df);
                    }
                }
            }
        }
    } else {
        // exact fallback: direct scan of this batch's s_map
        const float4* base = tok4 + (size_t)b * (NPIX / 4);
        for (int it = 0; it < 64; ++it) {
            int j = it * 256 + tid;
            float4 v = base[j];
            int px = j * 4;
            float fv[4] = {v.x, v.y, v.z, v.w};
            #pragma unroll
            for (int q = 0; q < 4; ++q) {
                if (vkey(fv[q]) == sb) {
                    uint32_t p = atomicAdd(&fcnt, 1u);
                    if (p < FCAP) {
                        fvb[p] = __float_as_uint(fv[q]);
                        fvi[p] = (uint32_t)(px + q);
                        fdf[p] = 0.f;   // computed on demand below
                    }
                }
            }
        }
    }
    __syncthreads();
    const uint32_t cnt = min(fcnt, (uint32_t)FCAP);

    float acc = (tid == 0) ? sh_sa : 0.f;
    if (tid < SEGS) acc += pk1[b * SEGS + tid];   // this batch's base partials

    for (uint32_t j = tid; j < cnt; j += 256) {
        const uint32_t mb = fvb[j], mi = fvi[j];
        uint32_t rank = 0;
        for (uint32_t i = 0; i < cnt; ++i) {
            uint32_t ob = fvb[i];
            rank += (ob > mb) || (ob == mb && fvi[i] < mi);
        }
        if (rank < rem) {
            if (fast) {
                acc += fdf[j];
            } else {
                size_t idx = (size_t)b * NPIX + mi;   // mi < NPIX (masked/built)
                float2 S = sc2[idx];
                float2 G = gn2[idx];
                float d = (S.x + G.x) - (S.y + G.y);
                float lp, llp; bce_from_d(d, lp, llp);
                acc += lp - llp;
            }
        }
    }
    float tot = block_reduce(acc);
    if (tid == 0) atomicAdd(out, -tot);   // 64 adds, out zeroed by k1
}

extern "C" void kernel_launch(void* const* d_in, const int* in_sizes, int n_in,
                              void* d_out, int out_size, void* d_ws, size_t ws_size,
                              hipStream_t stream) {
    const float* scores = (const float*)d_in[0];   // [B, N, 2]
    const float* smap   = (const float*)d_in[1];   // [B, N]
    const float* gumbel = (const float*)d_in[2];   // [B, N, 2]
    float* out = (float*)d_out;

    // workspace: every region fully written before read -> NO memset needed
    char* ws = (char*)d_ws;
    uint32_t* gc    = (uint32_t*)ws;  ws += (size_t)BATCH * SEGS * NB * 4;       // 2MB
    float*    gs    = (float*)ws;     ws += (size_t)BATCH * SEGS * NB * 4;       // 2MB
    float*    pk1   = (float*)ws;     ws += (size_t)BATCH * SEGS * 4;            // 8KB
    uint32_t* gcc   = (uint32_t*)ws;  ws += (size_t)BATCH * SEGS * 4;            // 8KB
    uint32_t* candw = (uint32_t*)ws;  ws += (size_t)BATCH * SEGS * CAPB * 3 * 4; // 4.7MB

    k1_hist_base<<<BATCH * SEGS, 256, 0, stream>>>(
        (const float4*)scores, (const float4*)gumbel, (const float2*)smap,
        gc, gs, pk1, candw, gcc, out);

    k4_finalize<<<BATCH, 256, 0, stream>>>(
        gc, gs, candw, gcc, pk1,
        (const float4*)smap, (const float2*)scores, (const float2*)gumbel, out);
}

// Round 9
// 136.296 us; speedup vs baseline: 1.1259x; 1.1259x over previous
//
#include <hip/hip_runtime.h>
#include <cstdint>

#define BATCH 64
#define NPIX 65536
#define TOPK 16384
#define NB 256
#define SEGS 32       // k1 blocks per batch
#define WLO 186       // candidate window low bin (threshold bin ~192)
#define WHI 198       // candidate window high bin
#define NWBIN (WHI - WLO + 1)
#define CAPB 192      // per-block window-candidate slots (expect ~104, sigma~10)
#define WCAP 4096     // per-batch staged window candidates in k4 (expect ~3328, sigma~56)
#define FCAP 1024     // threshold-bin rank buffer (expect ~256, sigma~16)

__device__ __forceinline__ float block_reduce(float acc) {
    __shared__ float w[4];
    __syncthreads();   // protect w against back-to-back calls
    #pragma unroll
    for (int off = 32; off > 0; off >>= 1) acc += __shfl_down(acc, off, 64);
    if ((threadIdx.x & 63) == 0) w[threadIdx.x >> 6] = acc;
    __syncthreads();
    return w[0] + w[1] + w[2] + w[3];
}

// p = softmax(a0,a1)[0] = sigmoid(d), d = a0-a1.
// lp = log p = min(d,0)-t ; llp = log(1-p) = -max(d,0)-t, t = log(1+exp(-|d|)).
__device__ __forceinline__ void bce_from_d(float d, float& lp, float& llp) {
    float t = __logf(1.f + __expf(-fabsf(d)));
    lp  = fmaxf(fminf(d, 0.f) - t, -100.f);
    llp = fmaxf(-fmaxf(d, 0.f) - t, -100.f);
}

__device__ __forceinline__ int vkey(float v) {
    return (int)fminf(v * 256.0f, 255.0f);   // monotone bucket map, v in [0,1)
}

// ---------------------------------------------------------------------------
// K1: one pass over all 80MB. NO per-pixel histogram atomics:
//   key > WHI  -> register accumulators (count, sum(diff))
//   key in win -> LDS compaction (one LDS atomic, ~5% of pixels)
//   key < WLO  -> nothing (llp only)
// Outputs (plain stores, fully written): pk1 (sum llp), psel (sum diff hi),
// phi (count hi, as float), gcc (raw window count), SoA candidate slots
// (zero-filled unused slots -> key 0, outside window = safe sentinel).
// Block 0 zeroes out[0].
// ---------------------------------------------------------------------------
__global__ __launch_bounds__(256) void k1_pass(
    const float4* __restrict__ sc, const float4* __restrict__ gn,
    const float2* __restrict__ tokp,
    float* __restrict__ pk1, float* __restrict__ psel, float* __restrict__ phi,
    uint32_t* __restrict__ gcc,
    uint32_t* __restrict__ cvb, uint32_t* __restrict__ cvi,
    uint32_t* __restrict__ cvd, float* __restrict__ out)
{
    __shared__ uint32_t bvb[CAPB], bvi[CAPB], bvd[CAPB];
    __shared__ uint32_t ccount;
    const int tid = threadIdx.x;
    if (tid < CAPB) { bvb[tid] = 0u; bvi[tid] = 0u; bvd[tid] = 0u; }
    if (tid == 0) { ccount = 0u; if (blockIdx.x == 0) out[0] = 0.f; }
    __syncthreads();

    const int b   = blockIdx.x >> 5;
    const int seg = blockIdx.x & (SEGS - 1);
    const int pairbase = b * (NPIX / 2) + seg * 1024;   // 1024 pairs / block
    float acc = 0.f, asel = 0.f, chi = 0.f;

    #pragma unroll
    for (int it = 0; it < 4; ++it) {
        int j = pairbase + it * 256 + tid;
        float4 s = sc[j];
        float4 g = gn[j];
        float2 tk = tokp[j];
        int px0 = (j - b * (NPIX / 2)) * 2;             // batch-local pixel idx
        {
            float d = (s.x + g.x) - (s.y + g.y);
            float lp, llp; bce_from_d(d, lp, llp);
            acc += llp;
            float diff = lp - llp;
            int k = vkey(tk.x);
            if (k > WHI) { asel += diff; chi += 1.f; }
            else if (k >= WLO) {
                uint32_t p = atomicAdd(&ccount, 1u);
                if (p < CAPB) {
                    bvb[p] = __float_as_uint(tk.x);
                    bvi[p] = (uint32_t)px0;
                    bvd[p] = __float_as_uint(diff);
                }
            }
        }
        {
            float d = (s.z + g.z) - (s.w + g.w);
            float lp, llp; bce_from_d(d, lp, llp);
            acc += llp;
            float diff = lp - llp;
            int k = vkey(tk.y);
            if (k > WHI) { asel += diff; chi += 1.f; }
            else if (k >= WLO) {
                uint32_t p = atomicAdd(&ccount, 1u);
                if (p < CAPB) {
                    bvb[p] = __float_as_uint(tk.y);
                    bvi[p] = (uint32_t)(px0 + 1);
                    bvd[p] = __float_as_uint(diff);
                }
            }
        }
    }
    __syncthreads();
    // copy full fixed-size slot block (unused slots are zero sentinels)
    const size_t cbase = (size_t)blockIdx.x * CAPB;
    if (tid < CAPB) {
        cvb[cbase + tid] = bvb[tid];
        cvi[cbase + tid] = bvi[tid];
        cvd[cbase + tid] = bvd[tid];
    }
    if (tid == 0) gcc[blockIdx.x] = ccount;

    float t1 = block_reduce(acc);
    float t2 = block_reduce(asel);
    float t3 = block_reduce(chi);
    if (tid == 0) {
        pk1[blockIdx.x]  = t1;
        psel[blockIdx.x] = t2;
        phi[blockIdx.x]  = t3;
    }
}

// ---------------------------------------------------------------------------
// K4: one block per batch. Stage all window candidates from SoA slots into
// LDS (zero-sentinel slots filter out via key check), build 13-bin counts,
// find sb/rem; add diffs for key > sb; exact-rank key == sb under
// (value desc, index asc) == lax.top_k tie order; add base sums; one
// atomicAdd(-total) into pre-zeroed out. Exact fallback if anything
// overflowed or sb left the window (prob ~1e-10).
// ---------------------------------------------------------------------------
__global__ __launch_bounds__(256) void k4_finalize(
    const uint32_t* __restrict__ cvb, const uint32_t* __restrict__ cvi,
    const uint32_t* __restrict__ cvd, const uint32_t* __restrict__ gcc,
    const float* __restrict__ pk1, const float* __restrict__ psel,
    const float* __restrict__ phi,
    const float4* __restrict__ tok4,
    const float2* __restrict__ sc2, const float2* __restrict__ gn2,
    float* __restrict__ out)
{
    __shared__ uint32_t wcv[WCAP], wci[WCAP];
    __shared__ float    wcd[WCAP];
    __shared__ uint32_t fvb[FCAP], fvi[FCAP];
    __shared__ float    fdf[FCAP];
    __shared__ uint32_t fh[NB];          // fallback histogram
    __shared__ uint32_t wc[NWBIN];
    __shared__ uint32_t wcnt, fcnt;
    __shared__ int      sh_sb, sh_ovf;
    __shared__ uint32_t sh_rem;
    __shared__ float    shseg[SEGS];

    const int b = blockIdx.x, tid = threadIdx.x;
    if (tid == 0) { wcnt = 0u; fcnt = 0u; sh_ovf = 0; sh_sb = -1; sh_rem = 1u; }
    if (tid < NWBIN) wc[tid] = 0u;
    __syncthreads();

    // --- stage window candidates (coalesced SoA reads over all slots) ---
    const size_t base = (size_t)b * SEGS * CAPB;
    for (int t = tid; t < SEGS * CAPB; t += 256) {
        uint32_t vb = cvb[base + t];
        int k = vkey(__uint_as_float(vb));
        if (k >= WLO && k <= WHI) {
            uint32_t p = atomicAdd(&wcnt, 1u);
            if (p < WCAP) {
                wcv[p] = vb;
                wci[p] = cvi[base + t] & (NPIX - 1);
                wcd[p] = __uint_as_float(cvd[base + t]);
                atomicAdd(&wc[k - WLO], 1u);
            }
        }
    }
    if (tid < SEGS && gcc[b * SEGS + tid] > CAPB) sh_ovf = 1;
    if (tid < SEGS) shseg[tid] = phi[b * SEGS + tid];
    __syncthreads();

    // --- find threshold bin within window (thread 0, 13 steps) ---
    if (tid == 0) {
        if (wcnt > WCAP) sh_ovf = 1;
        float chf = 0.f;
        for (int i = 0; i < SEGS; ++i) chf += shseg[i];
        uint32_t cnt_hi = (uint32_t)(chf + 0.5f);      // exact (integer-valued)
        if (cnt_hi >= TOPK) sh_ovf = 1;                // sb above window
        else {
            uint32_t cum = cnt_hi;                     // S[WHI+1]
            int found = -1; uint32_t rem = 1u;
            for (int j = WHI; j >= WLO; --j) {
                uint32_t nc = cum + wc[j - WLO];       // S[j]
                if (nc >= TOPK) { found = j; rem = TOPK - cum; break; }
                cum = nc;
            }
            if (found < 0) sh_ovf = 1;                 // sb below window
            else { sh_sb = found; sh_rem = rem; }
        }
    }
    __syncthreads();
    bool fast = (sh_ovf == 0);
    int sb = sh_sb;
    float acc = 0.f;
    if (tid < SEGS) acc += pk1[b * SEGS + tid];        // base llp (always exact)

    if (fast) {
        if (tid < SEGS) acc += psel[b * SEGS + tid];   // key > WHI diffs
        // filter staged candidates: > sb -> add; == sb -> rank buffer
        uint32_t nstage = min(wcnt, (uint32_t)WCAP);
        for (uint32_t j = tid; j < nstage; j += 256) {
            int k = vkey(__uint_as_float(wcv[j]));
            if (k > sb) acc += wcd[j];
            else if (k == sb) {
                uint32_t p = atomicAdd(&fcnt, 1u);
                if (p < FCAP) { fvb[p] = wcv[j]; fvi[p] = wci[j]; fdf[p] = wcd[j]; }
            }
        }
        __syncthreads();
        if (fcnt > FCAP) fast = false;                 // uniform (shared) decision
        if (fast) {
            const uint32_t cnt = fcnt, rem = sh_rem;
            for (uint32_t j = tid; j < cnt; j += 256) {
                const uint32_t mb = fvb[j], mi = fvi[j];
                uint32_t rank = 0;
                for (uint32_t i = 0; i < cnt; ++i) {
                    uint32_t ob = fvb[i];
                    rank += (ob > mb) || (ob == mb && fvi[i] < mi);
                }
                if (rank < rem) acc += fdf[j];
            }
        }
    }

    if (!fast) {
        // ---- exact fallback: full per-batch recount + recompute ----
        acc = (tid < SEGS) ? pk1[b * SEGS + tid] : 0.f;   // reset to base only
        for (int i = tid; i < NB; i += 256) fh[i] = 0u;
        if (tid == 0) fcnt = 0u;
        __syncthreads();
        const float4* tbase = tok4 + (size_t)b * (NPIX / 4);
        for (int it = 0; it < 64; ++it) {
            float4 v = tbase[it * 256 + tid];
            atomicAdd(&fh[vkey(v.x)], 1u);
            atomicAdd(&fh[vkey(v.y)], 1u);
            atomicAdd(&fh[vkey(v.z)], 1u);
            atomicAdd(&fh[vkey(v.w)], 1u);
        }
        __syncthreads();
        if (tid == 0) {
            uint32_t cum = 0; int bin = NB - 1;
            for (; bin > 0; --bin) {
                if (cum + fh[bin] >= TOPK) break;
                cum += fh[bin];
            }
            sh_sb = bin; sh_rem = TOPK - cum;
        }
        __syncthreads();
        const int sb2 = sh_sb; const uint32_t rem2 = sh_rem;
        for (int it = 0; it < 64; ++it) {
            int j = it * 256 + tid;
            float4 v = tbase[j];
            int px = j * 4;
            float fv[4] = {v.x, v.y, v.z, v.w};
            #pragma unroll
            for (int q = 0; q < 4; ++q) {
                int k = vkey(fv[q]);
                if (k > sb2) {
                    size_t idx = (size_t)b * NPIX + (px + q);
                    float2 S = sc2[idx]; float2 G = gn2[idx];
                    float d = (S.x + G.x) - (S.y + G.y);
                    float lp, llp; bce_from_d(d, lp, llp);
                    acc += lp - llp;
                } else if (k == sb2) {
                    uint32_t p = atomicAdd(&fcnt, 1u);
                    if (p < FCAP) { fvb[p] = __float_as_uint(fv[q]); fvi[p] = (uint32_t)(px + q); }
                }
            }
        }
        __syncthreads();
        const uint32_t cnt2 = min(fcnt, (uint32_t)FCAP);
        for (uint32_t j = tid; j < cnt2; j += 256) {
            const uint32_t mb = fvb[j], mi = fvi[j];
            uint32_t rank = 0;
            for (uint32_t i = 0; i < cnt2; ++i) {
                uint32_t ob = fvb[i];
                rank += (ob > mb) || (ob == mb && fvi[i] < mi);
            }
            if (rank < rem2) {
                size_t idx = (size_t)b * NPIX + (mi & (NPIX - 1));
                float2 S = sc2[idx]; float2 G = gn2[idx];
                float d = (S.x + G.x) - (S.y + G.y);
                float lp, llp; bce_from_d(d, lp, llp);
                acc += lp - llp;
            }
        }
    }

    float tot = block_reduce(acc);
    if (tid == 0) atomicAdd(out, -tot);    // 64 adds, out zeroed by k1
}

extern "C" void kernel_launch(void* const* d_in, const int* in_sizes, int n_in,
                              void* d_out, int out_size, void* d_ws, size_t ws_size,
                              hipStream_t stream) {
    const float* scores = (const float*)d_in[0];   // [B, N, 2]
    const float* smap   = (const float*)d_in[1];   // [B, N]
    const float* gumbel = (const float*)d_in[2];   // [B, N, 2]
    float* out = (float*)d_out;

    // workspace: every region fully written before read -> NO memset needed
    char* ws = (char*)d_ws;
    float*    pk1  = (float*)ws;     ws += (size_t)BATCH * SEGS * 4;         // 8KB
    float*    psel = (float*)ws;     ws += (size_t)BATCH * SEGS * 4;         // 8KB
    float*    phi  = (float*)ws;     ws += (size_t)BATCH * SEGS * 4;         // 8KB
    uint32_t* gcc  = (uint32_t*)ws;  ws += (size_t)BATCH * SEGS * 4;         // 8KB
    uint32_t* cvb  = (uint32_t*)ws;  ws += (size_t)BATCH * SEGS * CAPB * 4;  // 1.5MB
    uint32_t* cvi  = (uint32_t*)ws;  ws += (size_t)BATCH * SEGS * CAPB * 4;  // 1.5MB
    uint32_t* cvd  = (uint32_t*)ws;  ws += (size_t)BATCH * SEGS * CAPB * 4;  // 1.5MB

    k1_pass<<<BATCH * SEGS, 256, 0, stream>>>(
        (const float4*)scores, (const float4*)gumbel, (const float2*)smap,
        pk1, psel, phi, gcc, cvb, cvi, cvd, out);

    k4_finalize<<<BATCH, 256, 0, stream>>>(
        cvb, cvi, cvd, gcc, pk1, psel, phi,
        (const float4*)smap, (const float2*)scores, (const float2*)gumbel, out);
}